// Round 8
// baseline (513.440 us; speedup 1.0000x reference)
//
#include <hip/hip_runtime.h>

#define Bn 128
#define Sn 512
#define Hn 1024
#define Ln 4

typedef float nfloat4 __attribute__((ext_vector_type(4)));
typedef __attribute__((ext_vector_type(8))) short short8;
typedef __attribute__((ext_vector_type(4))) float f32x4;

__device__ __forceinline__ float sigmoidf_(float x) { return 1.0f / (1.0f + __expf(-x)); }

// round-to-nearest-even fp32 -> bf16 (bit pattern in ushort)
__device__ __forceinline__ unsigned short bf16hi(float f) {
  unsigned u = __float_as_uint(f);
  u = u + 0x7FFFu + ((u >> 16) & 1u);
  return (unsigned short)(u >> 16);
}
__device__ __forceinline__ float bf16tof(unsigned short h) {
  return __uint_as_float(((unsigned)h) << 16);
}

// ---------------- K1: fused lengths + stable descending argsort (1 block; R3-verified) ----------------
__global__ __launch_bounds__(1024) void lensort_kernel(const int* __restrict__ x,
                                                       int* __restrict__ lengths,
                                                       int* __restrict__ rank,
                                                       int* __restrict__ tok_sorted,
                                                       int* __restrict__ bs_last) {
  __shared__ int pc[128][8];
  __shared__ int sl[128];
  __shared__ int cnt;
  const int t = threadIdx.x;
  const int row = t >> 3, seg = t & 7;
  int c = 0;
  const int4* xp = (const int4*)x + row * 128 + seg * 16;
#pragma unroll
  for (int i = 0; i < 16; i++) {
    int4 v = xp[i];
    c += (v.x > 0) + (v.y > 0) + (v.z > 0) + (v.w > 0);
  }
  pc[row][seg] = c;
  if (t == 0) cnt = 0;
  __syncthreads();
  int len = 0;
  if (t < 128) {
#pragma unroll
    for (int i = 0; i < 8; i++) len += pc[t][i];
    sl[t] = len;
    lengths[t] = len;
  }
  __syncthreads();
  if (t < 128) {
    int r = 0;
    for (int b2 = 0; b2 < 128; b2++) {
      int l2 = sl[b2];
      r += (l2 > len) || (l2 == len && b2 < t);
    }
    rank[t] = r;
    tok_sorted[r] = x[t * Sn];
    if (len >= Sn) atomicAdd(&cnt, 1);
  }
  __syncthreads();
  if (t == 0) bs_last[0] = cnt;
}

// ---------------- K2: gather emb rows (sorted) + split to bf16 hi/lo (R7-verified) ----------------
__global__ __launch_bounds__(256) void gather_cvt(const int* __restrict__ tok_sorted,
                                                  const float* __restrict__ emb,
                                                  unsigned short* __restrict__ xhi,
                                                  unsigned short* __restrict__ xlo) {
  const int r = blockIdx.x, t = threadIdx.x;
  const int tok = tok_sorted[r];
  float4 v = ((const float4*)emb)[(size_t)tok * 256 + t];
  float f[4] = {v.x, v.y, v.z, v.w};
  unsigned short hh[4], ll[4];
#pragma unroll
  for (int j = 0; j < 4; j++) {
    hh[j] = bf16hi(f[j]);
    ll[j] = bf16hi(f[j] - bf16tof(hh[j]));
  }
  ((ushort4*)xhi)[r * 256 + t] = make_ushort4(hh[0], hh[1], hh[2], hh[3]);
  ((ushort4*)xlo)[r * 256 + t] = make_ushort4(ll[0], ll[1], ll[2], ll[3]);
}

// ---------------- K3: fused no-split-K MFMA GEMM + LSTM-cell epilogue + zero-writer blocks ----------------
// grid = 256, 256 threads:
//  blocks 0..63: compute m0 = blockIdx*16 gate-cols for ALL 3 gates (i,g,o), full K=1024,
//    bf16x3 emulation. W[48 rows][256 k-chunk] -> LDS hi/lo (each W elem read+converted once).
//    Wave w: A-rows w*32..+31 (2 row-tiles), 3 col-tiles (one per gate). Epilogue applies
//    sigmoid/tanh and writes h (fp32 + bf16 hi/lo for next layer) and masked sh/sc.
//    Fragment maps (16x16x32, m89-verified via R7): A row=lane&15, k=(lane>>4)*8+j;
//    B col=lane&15; D col=lane&15, row=(lane>>4)*4+reg.
//  blocks 64..255: independent zero-writers for out t-band [32+120*layer, 32+120*(layer+1)),
//    tt >= len[b] only. No shared barriers with compute blocks (R3 lesson: decouple by BLOCK,
//    not by wave). bf16 ping-pong buffers live at out t-slabs [16,18) -> disjoint (t>=32).
__global__ __launch_bounds__(256) void gemm_fused(const unsigned short* __restrict__ xhi,
                                                  const unsigned short* __restrict__ xlo,
                                                  const float* __restrict__ Wl,
                                                  const float* __restrict__ bih,
                                                  const float* __restrict__ bhh,
                                                  const int* __restrict__ bs_last,
                                                  const int* __restrict__ lengths,
                                                  float* __restrict__ xt_out,
                                                  float* __restrict__ sh,
                                                  float* __restrict__ sc,
                                                  unsigned short* __restrict__ xhi_out,
                                                  unsigned short* __restrict__ xlo_out,
                                                  float* __restrict__ out,
                                                  const int layer) {
  __shared__ unsigned short Whi[48][264];  // 48 W rows (3 gates x 16 cols), 256 k + 8 pad
  __shared__ unsigned short Wlo[48][264];  // row stride 528 B = 33 x 16 B -> +1 bank per row
  const int t = threadIdx.x;

  if (blockIdx.x >= 64) {
    // ---------------- zero-writer block ----------------
    const int z = blockIdx.x - 64;          // 0..191
    const int p0 = z * 80;                  // 120 t x 128 b = 15360 pairs / 192 blocks
    const int tb0 = 32 + layer * 120;
    const nfloat4 zz = (nfloat4)0.0f;
    for (int i = 0; i < 80; i++) {
      const int p = p0 + i;
      const int tt = tb0 + (p >> 7);
      const int b = p & 127;
      if (tt >= lengths[b]) {
        __builtin_nontemporal_store(zz, (nfloat4*)out + ((size_t)tt * 128 + b) * 256 + t);
      }
    }
    return;
  }

  // ---------------- compute block ----------------
  const int m0 = blockIdx.x * 16;           // gate-col slice [m0, m0+16)
  const int w = t >> 6, l = t & 63;
  const int lrow = l & 15;
  const int lk8 = (l >> 4) * 8;

  // prologue: load W chunk 0 raw fp32 into registers (12 float4/thread = 48 rows x 256 k)
  float4 wreg[12];
#pragma unroll
  for (int i = 0; i < 12; i++) {
    const int vi = i * 256 + t;
    const int c = vi >> 6;                  // 0..47
    const int k4 = (vi & 63) * 4;           // 0..252
    const int g = c >> 4;
    const int wr = ((g == 0) ? 0 : ((g == 1) ? 2048 : 3072)) + m0 + (c & 15);
    wreg[i] = *(const float4*)&Wl[(size_t)wr * 1024 + k4];
  }

  f32x4 acc[2][3];
#pragma unroll
  for (int rt = 0; rt < 2; rt++)
#pragma unroll
    for (int q = 0; q < 3; q++) acc[rt][q] = (f32x4)0.0f;

#pragma unroll
  for (int kc = 0; kc < 4; kc++) {
    const int k0 = kc * 256;
    __syncthreads();                        // prev MFMA done reading LDS
    // convert wreg -> LDS hi/lo
#pragma unroll
    for (int i = 0; i < 12; i++) {
      const int vi = i * 256 + t;
      const int c = vi >> 6;
      const int k4 = (vi & 63) * 4;
      float f[4] = {wreg[i].x, wreg[i].y, wreg[i].z, wreg[i].w};
      unsigned short hh[4], ll[4];
#pragma unroll
      for (int j = 0; j < 4; j++) {
        hh[j] = bf16hi(f[j]);
        ll[j] = bf16hi(f[j] - bf16tof(hh[j]));
      }
      *(ushort4*)&Whi[c][k4] = make_ushort4(hh[0], hh[1], hh[2], hh[3]);
      *(ushort4*)&Wlo[c][k4] = make_ushort4(ll[0], ll[1], ll[2], ll[3]);
    }
    // reload wreg with next chunk (in flight during MFMA phase; consumed after next barrier)
    if (kc < 3) {
      const int kn = k0 + 256;
#pragma unroll
      for (int i = 0; i < 12; i++) {
        const int vi = i * 256 + t;
        const int c = vi >> 6;
        const int k4 = (vi & 63) * 4;
        const int g = c >> 4;
        const int wr = ((g == 0) ? 0 : ((g == 1) ? 2048 : 3072)) + m0 + (c & 15);
        wreg[i] = *(const float4*)&Wl[(size_t)wr * 1024 + kn + k4];
      }
    }
    __syncthreads();                        // LDS tile ready
    const unsigned short* xh0 = xhi + (size_t)(w * 32 + lrow) * 1024 + k0 + lk8;
    const unsigned short* xl0 = xlo + (size_t)(w * 32 + lrow) * 1024 + k0 + lk8;
#pragma unroll
    for (int ks = 0; ks < 8; ks++) {
      const int kk = ks * 32;
      short8 ah[2], al[2], bh[3], bl[3];
#pragma unroll
      for (int rt = 0; rt < 2; rt++) {
        ah[rt] = *(const short8*)(xh0 + rt * 16 * 1024 + kk);
        al[rt] = *(const short8*)(xl0 + rt * 16 * 1024 + kk);
      }
#pragma unroll
      for (int q = 0; q < 3; q++) {
        bh[q] = *(const short8*)&Whi[q * 16 + lrow][kk + lk8];
        bl[q] = *(const short8*)&Wlo[q * 16 + lrow][kk + lk8];
      }
#pragma unroll
      for (int rt = 0; rt < 2; rt++)
#pragma unroll
        for (int q = 0; q < 3; q++) {
          acc[rt][q] = __builtin_amdgcn_mfma_f32_16x16x32_bf16(ah[rt], bh[q], acc[rt][q], 0, 0, 0);
          acc[rt][q] = __builtin_amdgcn_mfma_f32_16x16x32_bf16(ah[rt], bl[q], acc[rt][q], 0, 0, 0);
          acc[rt][q] = __builtin_amdgcn_mfma_f32_16x16x32_bf16(al[rt], bh[q], acc[rt][q], 0, 0, 0);
        }
    }
  }

  // ---------------- epilogue: LSTM cell + stores ----------------
  const int bs = bs_last[0];
  const int m = m0 + lrow;
  const float bi = bih[m] + bhh[m];
  const float bg = bih[2048 + m] + bhh[2048 + m];
  const float bo = bih[3072 + m] + bhh[3072 + m];
#pragma unroll
  for (int rt = 0; rt < 2; rt++) {
    const int rb = w * 32 + rt * 16 + (l >> 4) * 4;   // D row = (lane>>4)*4 + reg
#pragma unroll
    for (int j = 0; j < 4; j++) {
      const int r = rb + j;
      const float iv = acc[rt][0][j] + bi;
      const float gv = acc[rt][1][j] + bg;
      const float ov = acc[rt][2][j] + bo;
      const float cc = sigmoidf_(iv) * tanhf(gv);
      const float hh = sigmoidf_(ov) * tanhf(cc);
      const float msk = (r < bs) ? 1.0f : 0.0f;
      xt_out[(size_t)r * 1024 + m] = hh;
      sh[(size_t)r * 1024 + m] = msk * hh;
      sc[(size_t)r * 1024 + m] = msk * cc;
      const unsigned short hb = bf16hi(hh);
      xhi_out[(size_t)r * 1024 + m] = hb;
      xlo_out[(size_t)r * 1024 + m] = bf16hi(hh - bf16tof(hb));
    }
  }
}

// ---------------- K4: output valid region + t<32 zero residual (R3-verified) ----------------
// zeros for t in [max(32,len),512) already written by gemm_fused zero blocks.
__global__ __launch_bounds__(256) void bcast_kernel(const float* __restrict__ hfin,
                                                    const int* __restrict__ lengths,
                                                    const int* __restrict__ rank,
                                                    float* __restrict__ out) {
  const int b = blockIdx.x & 127;
  const int c = blockIdx.x >> 7;      // 0..7
  const int len = lengths[b];
  const int t0 = c * 64;
  if (t0 < len) {
    const nfloat4 v = ((const nfloat4*)hfin)[rank[b] * 256 + threadIdx.x];
    const int hi = (len < t0 + 64) ? len : (t0 + 64);
    nfloat4* p = (nfloat4*)out + ((size_t)t0 * 128 + b) * 256 + threadIdx.x;
    for (int tt = t0; tt < hi; tt++) {
      __builtin_nontemporal_store(v, p);
      p += 32768;                      // one t step = 128*1024 floats
    }
  }
  if (c == 0 && len < 32) {
    const nfloat4 z = (nfloat4)0.0f;
    nfloat4* pz = (nfloat4*)out + ((size_t)len * 128 + b) * 256 + threadIdx.x;
    for (int tt = len; tt < 32; tt++) {
      __builtin_nontemporal_store(z, pz);
      pz += 32768;
    }
  }
}

extern "C" void kernel_launch(void* const* d_in, const int* in_sizes, int n_in,
                              void* d_out, int out_size, void* d_ws, size_t ws_size,
                              hipStream_t stream) {
  const int* x = (const int*)d_in[0];
  const float* emb = (const float*)d_in[1];
  const float* W_ih = (const float*)d_in[2];
  // d_in[3] = W_hh: NEVER multiplied (h0 == 0); only b_hh is added.
  const float* b_ih = (const float*)d_in[4];
  const float* b_hh = (const float*)d_in[5];

  float* out = (float*)d_out;
  float* sh = out + (size_t)Sn * Bn * Hn;   // state_h [L,B,H]
  float* sc = sh + (size_t)Ln * Bn * Hn;    // state_c [L,B,H]
  // bf16 hi/lo ping-pong buffers at out t-slabs [16,18); zero blocks write t>=32 only;
  // bcast overwrites the slabs at the very end (after all reads).
  unsigned short* bfbase = (unsigned short*)(out + (size_t)2097152);
  unsigned short* xhiA = bfbase;
  unsigned short* xloA = bfbase + 131072;
  unsigned short* xhiB = bfbase + 262144;
  unsigned short* xloB = bfbase + 393216;

  char* ws = (char*)d_ws;
  int* lengths = (int*)ws;                  // [128]
  int* rank = lengths + 128;                // [128]
  int* tok_sorted = rank + 128;             // [128]
  int* bs_last = tok_sorted + 128;          // [1]
  float* xtA = (float*)(ws + 4096);         // [128,1024] fp32 h (for bcast)
  float* xtB = xtA + 128 * 1024;

  lensort_kernel<<<1, 1024, 0, stream>>>(x, lengths, rank, tok_sorted, bs_last);
  gather_cvt<<<128, 256, 0, stream>>>(tok_sorted, emb, xhiA, xloA);

  float* xtF[2] = {xtA, xtB};
  unsigned short* hiP[2] = {xhiA, xhiB};
  unsigned short* loP[2] = {xloA, xloB};
  int cur = 0;
  for (int l = 0; l < Ln; l++) {
    const int nxt = cur ^ 1;
    gemm_fused<<<256, 256, 0, stream>>>(hiP[cur], loP[cur], W_ih + (size_t)l * 4 * Hn * Hn,
                                        b_ih + l * 4 * Hn, b_hh + l * 4 * Hn, bs_last, lengths,
                                        xtF[l & 1], sh + (size_t)l * Bn * Hn,
                                        sc + (size_t)l * Bn * Hn, hiP[nxt], loP[nxt], out, l);
    cur = nxt;
  }
  // top-layer h fp32 = xtF[3&1] = xtB
  bcast_kernel<<<1024, 256, 0, stream>>>(xtF[1], lengths, rank, out);
}